// Round 4
// baseline (1672.768 us; speedup 1.0000x reference)
//
#include <hip/hip_runtime.h>
#include <hip/hip_bf16.h>
#include <math.h>

#define S_LEN 4096
#define HID   2048
#define NHEADS 8
#define NKVH   4
#define HDIM   256
#define FFN    8192
#define WIN    4096

typedef __bf16 bf16_t;
typedef __bf16 bf16x4 __attribute__((ext_vector_type(4)));
typedef __bf16 bf16x8 __attribute__((ext_vector_type(8)));
typedef float  floatx4 __attribute__((ext_vector_type(4)));

// ---------------- reduction helpers (256-thread blocks, 4 waves) ----------------
__device__ inline float waveReduceSum(float v) {
#pragma unroll
    for (int o = 32; o > 0; o >>= 1) v += __shfl_xor(v, o);
    return v;
}
__device__ inline float blockReduceSum(float v, float* sh) {
    int tid = threadIdx.x;
    v = waveReduceSum(v);
    if ((tid & 63) == 0) sh[tid >> 6] = v;
    __syncthreads();
    v = sh[0] + sh[1] + sh[2] + sh[3];
    __syncthreads();
    return v;
}

// ---------------- transpose + cast to bf16: in[R][C] -> out[C][R] ----------------
template <typename T>
__global__ __launch_bounds__(256) void transpose_bf16_kernel(const T* __restrict__ in,
                                                             bf16_t* __restrict__ out,
                                                             int R, int C) {
    __shared__ float tile[32][33];
    int tx = threadIdx.x & 31;
    int ty = threadIdx.x >> 5;  // 0..7
    int c0 = blockIdx.x * 32;
    int r0 = blockIdx.y * 32;
#pragma unroll
    for (int i = 0; i < 4; ++i)
        tile[ty + i * 8][tx] = (float)in[(long long)(r0 + ty + i * 8) * C + c0 + tx];
    __syncthreads();
#pragma unroll
    for (int i = 0; i < 4; ++i)
        out[(long long)(c0 + ty + i * 8) * R + r0 + tx] = (bf16_t)tile[tx][ty + i * 8];
}

// ---------------- RMSNorm (fp32 in -> bf16 out), one row per block ----------------
__global__ __launch_bounds__(256) void rmsnorm_kernel(const float* __restrict__ x,
                                                      const float* __restrict__ w,
                                                      bf16_t* __restrict__ out) {
    __shared__ float sh[4];
    int row = blockIdx.x;
    const float* xr = x + (long long)row * HID;
    float v[8];
    float ss = 0.f;
#pragma unroll
    for (int i = 0; i < 8; ++i) {
        v[i] = xr[threadIdx.x + i * 256];
        ss += v[i] * v[i];
    }
    ss = blockReduceSum(ss, sh);
    float sc = rsqrtf(ss * (1.0f / HID) + 1e-6f);
#pragma unroll
    for (int i = 0; i < 8; ++i) {
        int c = threadIdx.x + i * 256;
        out[(long long)row * HID + c] = (bf16_t)(v[i] * sc * w[c]);
    }
}

// ---------------- RoPE in-place on bf16 q [S,NH*HD] and k [S,NKV*HD] ----------------
__global__ __launch_bounds__(256) void rope_kernel(bf16_t* __restrict__ q,
                                                   bf16_t* __restrict__ k,
                                                   const int* __restrict__ pos_ids) {
    int s = blockIdx.x;
    float p = (float)pos_ids[s];
    for (int t = threadIdx.x; t < (NHEADS + NKVH) * (HDIM / 2); t += 256) {
        int head = t >> 7;        // 0..11
        int i = t & 127;          // rotary pair index
        float inv = expf(-(2.0f * (float)i / (float)HDIM) * 9.210340371976184f);  // theta^-2i/HD
        float f = p * inv;
        float sn, cs;
        sincosf(f, &sn, &cs);
        bf16_t* base = (head < NHEADS) ? (q + (long long)s * HID + head * HDIM)
                                       : (k + (long long)s * (NKVH * HDIM) + (head - NHEADS) * HDIM);
        float a = (float)base[i];
        float b = (float)base[i + 128];
        base[i]       = (bf16_t)(a * cs - b * sn);
        base[i + 128] = (bf16_t)(b * cs + a * sn);
    }
}

// ---------------- flash attention v4 ----------------
// Grid: (16 pairs, NHEADS, 4 kquarters) = 512 blocks, 256 threads = 4 waves.
// Block handles q-tiles {x, 31-x} of 128 rows; wave owns 32 queries (2 sets of 16).
// Every K/V fragment read from LDS feeds 2 MFMAs (one per q-set) -> read:MFMA
// ratio ~= GEMM's. LDS is fragment-ordered (slot = frag*64+lane) so all
// ds_read_b128 are lane-linear (conflict-free). Keys split across 4 quarters
// (blockIdx.z); partial O (normalized) + (m,l) per quarter, combined after.
__global__ __launch_bounds__(256, 2) void flash_attn_kernel(const bf16_t* __restrict__ qg,
                                                            const bf16_t* __restrict__ kg,
                                                            const bf16_t* __restrict__ vTg,
                                                            bf16_t* __restrict__ opb,
                                                            float* __restrict__ mlb,
                                                            const int* __restrict__ amask) {
    __shared__ bf16_t sK[64 * 256];   // 32 KiB, 32 frags (f=ks*4+ni): lane(tl,q) = K[(f&3)*16+tl][dchunk=(f>>2)*4+q]
    __shared__ bf16_t sV[256 * 64];   // 32 KiB, 32 frags (f=k2*16+dt): lane(tl,q) = V^T[(f&15)*16+tl][kchunk=(f>>4)*4+q]

    const int h = blockIdx.y;
    const int jq = blockIdx.z;
    const int tid = threadIdx.x;
    const int lane = tid & 63;
    const int w = tid >> 6;
    const int tl = lane & 15;
    const int quad = lane >> 4;

    const bf16_t* Qh = qg + h * HDIM;
    const bf16_t* Kh = kg + (h >> 1) * HDIM;
    const bf16_t* Vh = vTg + (long long)(h >> 1) * HDIM * S_LEN;
    bf16_t* Op = opb + (long long)jq * (S_LEN * HID);
    float* mlj = mlb + (long long)jq * (NHEADS * S_LEN * 2);
    bf16_t* sP = sK + w * (32 * 72);  // per-wave P [32 q][64 k], stride 72, aliases dead sK

#pragma unroll 1
    for (int half = 0; half < 2; ++half) {
        const int qi = half ? (31 - blockIdx.x) : blockIdx.x;
        const int qr0 = qi * 128;
        const int T = 2 * qi + 2;
        const int t0 = (T * jq) >> 2;
        const int t1 = (T * (jq + 1)) >> 2;
        const int irow = qr0 + w * 32 + tl;  // set-0 query row; set 1 = +16

        // Q fragments (B-operand: n=tl=query, k=quad*8+j within 32-slice ks)
        bf16x8 qf[2][8];
#pragma unroll
        for (int s = 0; s < 2; ++s) {
            const bf16_t* qrow = Qh + (long long)(irow + s * 16) * HID;
#pragma unroll
            for (int ks = 0; ks < 8; ++ks)
                qf[s][ks] = *(const bf16x8*)(qrow + (ks * 4 + quad) * 8);
        }

        floatx4 oacc[2][16] = {};
        float m_i[2] = {-3e38f, -3e38f};
        float l_i[2] = {0.f, 0.f};

        for (int t = t0; t < t1; ++t) {
            const int kt = t * 64;
            // ---- stage K & V^T tiles, fragment-ordered, 16B/lane ----
#pragma unroll
            for (int it = 0; it < 8; ++it) {
                int f = it * 4 + w;
                {
                    int row = (f & 3) * 16 + tl;
                    int dc = (f >> 2) * 4 + quad;
                    const bf16_t* src = Kh + (long long)(kt + row) * (NKVH * HDIM) + dc * 8;
                    __builtin_amdgcn_global_load_lds((const __attribute__((address_space(1))) void*)src,
                                                     (__attribute__((address_space(3))) void*)(sK + (it * 256 + tid) * 8),
                                                     16, 0, 0);
                }
                {
                    int d = (f & 15) * 16 + tl;
                    int kc = (f >> 4) * 4 + quad;
                    const bf16_t* src = Vh + (long long)d * S_LEN + kt + kc * 8;
                    __builtin_amdgcn_global_load_lds((const __attribute__((address_space(1))) void*)src,
                                                     (__attribute__((address_space(3))) void*)(sV + (it * 256 + tid) * 8),
                                                     16, 0, 0);
                }
            }
            __builtin_amdgcn_s_waitcnt(0x0f70);  // vmcnt(0)
            __syncthreads();

            // ---- S^T = K Q^T : lane holds S[q=tl(set)][key=kt+ni*16+quad*4+r] ----
            floatx4 sacc[2][4] = {};
#pragma unroll
            for (int ks = 0; ks < 8; ++ks) {
#pragma unroll
                for (int ni = 0; ni < 4; ++ni) {
                    bf16x8 kf = *(const bf16x8*)(sK + ((ks * 4 + ni) * 64 + lane) * 8);
                    sacc[0][ni] = __builtin_amdgcn_mfma_f32_16x16x32_bf16(kf, qf[0][ks], sacc[0][ni], 0, 0, 0);
                    sacc[1][ni] = __builtin_amdgcn_mfma_f32_16x16x32_bf16(kf, qf[1][ks], sacc[1][ni], 0, 0, 0);
                }
            }
            __syncthreads();  // all waves done with sK; sP (alias) writable

            // ---- online softmax per set ----
            int4 am4[4];
#pragma unroll
            for (int ni = 0; ni < 4; ++ni) am4[ni] = *(const int4*)(amask + kt + ni * 16 + quad * 4);
#pragma unroll
            for (int s = 0; s < 2; ++s) {
                const int ir = irow + s * 16;
                float sv[4][4];
                float mx = -3e38f;
#pragma unroll
                for (int ni = 0; ni < 4; ++ni) {
#pragma unroll
                    for (int r = 0; r < 4; ++r) {
                        int jk = kt + ni * 16 + quad * 4 + r;
                        int amr = (r == 0) ? am4[ni].x : (r == 1) ? am4[ni].y : (r == 2) ? am4[ni].z : am4[ni].w;
                        bool valid = (jk <= ir) && (jk > ir - WIN) && (amr > 0);
                        float x = valid ? sacc[s][ni][r] * 0.0625f : -3e38f;
                        sv[ni][r] = x;
                        mx = fmaxf(mx, x);
                    }
                }
                mx = fmaxf(mx, __shfl_xor(mx, 16));
                mx = fmaxf(mx, __shfl_xor(mx, 32));
                if (__any(mx > m_i[s])) {       // rescale only when any query's max moved
                    float mnew = fmaxf(m_i[s], mx);
                    float alpha = __expf(m_i[s] - mnew);
                    m_i[s] = mnew;
                    l_i[s] *= alpha;
                    floatx4 av;
#pragma unroll
                    for (int r = 0; r < 4; ++r) av[r] = __shfl(alpha, quad * 4 + r);
#pragma unroll
                    for (int dt = 0; dt < 16; ++dt) oacc[s][dt] *= av;
                }
                float rs = 0.f;
#pragma unroll
                for (int ni = 0; ni < 4; ++ni) {
                    bf16x4 pk;
#pragma unroll
                    for (int r = 0; r < 4; ++r) {
                        float p = (sv[ni][r] > -1e37f) ? __expf(sv[ni][r] - m_i[s]) : 0.f;
                        rs += p;
                        pk[r] = (bf16_t)p;
                    }
                    *(bf16x4*)(sP + (s * 16 + tl) * 72 + ni * 16 + quad * 4) = pk;
                }
                rs += __shfl_xor(rs, 16);
                rs += __shfl_xor(rs, 32);
                l_i[s] += rs;
            }

            // ---- O += P V : vf read once, feeds both q-sets ----
#pragma unroll
            for (int k2 = 0; k2 < 2; ++k2) {
                bf16x8 pf0 = *(const bf16x8*)(sP + tl * 72 + k2 * 32 + quad * 8);
                bf16x8 pf1 = *(const bf16x8*)(sP + (16 + tl) * 72 + k2 * 32 + quad * 8);
#pragma unroll
                for (int dt = 0; dt < 16; ++dt) {
                    bf16x8 vf = *(const bf16x8*)(sV + ((k2 * 16 + dt) * 64 + lane) * 8);
                    oacc[0][dt] = __builtin_amdgcn_mfma_f32_16x16x32_bf16(pf0, vf, oacc[0][dt], 0, 0, 0);
                    oacc[1][dt] = __builtin_amdgcn_mfma_f32_16x16x32_bf16(pf1, vf, oacc[1][dt], 0, 0, 0);
                }
            }
            __syncthreads();  // protect sK/sV/sP before next staging
        }

        // ---- epilogue: normalized partial O + (m,l) ----
#pragma unroll
        for (int s = 0; s < 2; ++s) {
            floatx4 inv;
#pragma unroll
            for (int r = 0; r < 4; ++r) {
                float lv = __shfl(l_i[s], quad * 4 + r);
                inv[r] = (lv > 0.f) ? 1.0f / lv : 0.f;
            }
#pragma unroll
            for (int dt = 0; dt < 16; ++dt) {
#pragma unroll
                for (int r = 0; r < 4; ++r) {
                    long long row = qr0 + w * 32 + s * 16 + quad * 4 + r;
                    Op[row * HID + h * HDIM + dt * 16 + tl] = (bf16_t)(oacc[s][dt][r] * inv[r]);
                }
            }
            if (quad == 0) {
                long long mi2 = ((long long)h * S_LEN + irow + s * 16) * 2;
                mlj[mi2] = m_i[s];
                mlj[mi2 + 1] = l_i[s];
            }
        }
    }
}

// ---------------- combine 4 k-quarter partials -> attnb ----------------
__global__ __launch_bounds__(256) void combine_kernel(const bf16_t* __restrict__ opb,
                                                      const float* __restrict__ mlb,
                                                      bf16_t* __restrict__ attnb) {
    int h = blockIdx.x;
    int row = blockIdx.y;
    int d = threadIdx.x;
    float m[4], l[4];
    float M = -3e38f;
#pragma unroll
    for (int j = 0; j < 4; ++j) {
        long long mi = (((long long)j * NHEADS + h) * S_LEN + row) * 2;
        m[j] = mlb[mi];
        l[j] = mlb[mi + 1];
        M = fmaxf(M, m[j]);
    }
    float wj[4], wsum = 0.f;
#pragma unroll
    for (int j = 0; j < 4; ++j) {
        wj[j] = (l[j] > 0.f) ? l[j] * __expf(m[j] - M) : 0.f;
        wsum += wj[j];
    }
    float inv = 1.0f / wsum;
    long long idx = (long long)row * HID + h * HDIM + d;
    float acc = 0.f;
#pragma unroll
    for (int j = 0; j < 4; ++j)
        acc += wj[j] * (float)opb[(long long)j * (S_LEN * HID) + idx];
    attnb[idx] = (bf16_t)(acc * inv);
}

// ---------------- MFMA GEMM: C[M,N] = A[M,K] * Bt[N,K]^T ----------------
// 128x128 tile, BK=64, 256 threads (2x2 waves of 64x64), global_load_lds staging,
// fragment-ordered LDS (lane-linear ds_read_b128, conflict-free).
// MODE: 0 = store bf16; 1 = fp32 store of aux+acc; 2 = bf16 store of gelu(aux)*acc.
template <int MODE>
__global__ __launch_bounds__(256) void gemm_kernel(const bf16_t* __restrict__ A, int lda,
                                                   const bf16_t* __restrict__ Bt, int ldb,
                                                   void* __restrict__ Cv, int ldc,
                                                   const void* __restrict__ aux, int K) {
    __shared__ bf16_t smem[2 * 128 * 64];
    bf16_t* sA = smem;            // 16 frags (f=kk*8+mg): lane = A[(f&7)*16+tl][kchunk=(f>>3)*4+quad]
    bf16_t* sB = smem + 128 * 64;

    const int tid = threadIdx.x;
    const int n0 = blockIdx.x * 128;
    const int m0 = blockIdx.y * 128;

    const int lane = tid & 63;
    const int wid = tid >> 6;
    const int wm = (wid >> 1) * 64;
    const int wn = (wid & 1) * 64;
    const int tl = lane & 15;
    const int quad = lane >> 4;

    floatx4 acc[4][4] = {};

    for (int k0 = 0; k0 < K; k0 += 64) {
#pragma unroll
        for (int it = 0; it < 4; ++it) {
            int f = it * 4 + wid;            // frag 0..15
            int row = (f & 7) * 16 + tl;
            int kc = (f >> 3) * 4 + quad;    // 0..7
            const bf16_t* ga = A + (long long)(m0 + row) * lda + k0 + kc * 8;
            __builtin_amdgcn_global_load_lds((const __attribute__((address_space(1))) void*)ga,
                                             (__attribute__((address_space(3))) void*)(sA + (it * 256 + tid) * 8),
                                             16, 0, 0);
            const bf16_t* gb = Bt + (long long)(n0 + row) * ldb + k0 + kc * 8;
            __builtin_amdgcn_global_load_lds((const __attribute__((address_space(1))) void*)gb,
                                             (__attribute__((address_space(3))) void*)(sB + (it * 256 + tid) * 8),
                                             16, 0, 0);
        }
        __builtin_amdgcn_s_waitcnt(0x0f70);  // vmcnt(0)
        __syncthreads();

#pragma unroll
        for (int kk = 0; kk < 2; ++kk) {
            bf16x8 af[4], bfr[4];
#pragma unroll
            for (int mi = 0; mi < 4; ++mi)
                af[mi] = *(const bf16x8*)(sA + ((kk * 8 + (wm >> 4) + mi) * 64 + lane) * 8);
#pragma unroll
            for (int ni = 0; ni < 4; ++ni)
                bfr[ni] = *(const bf16x8*)(sB + ((kk * 8 + (wn >> 4) + ni) * 64 + lane) * 8);
#pragma unroll
            for (int mi = 0; mi < 4; ++mi)
#pragma unroll
                for (int ni = 0; ni < 4; ++ni)
                    acc[mi][ni] = __builtin_amdgcn_mfma_f32_16x16x32_bf16(af[mi], bfr[ni], acc[mi][ni], 0, 0, 0);
        }
        __syncthreads();
    }

    // epilogue: C/D layout col=lane&15, row=quad*4+r
#pragma unroll
    for (int mi = 0; mi < 4; ++mi) {
#pragma unroll
        for (int ni = 0; ni < 4; ++ni) {
#pragma unroll
            for (int r = 0; r < 4; ++r) {
                int gr = m0 + wm + mi * 16 + quad * 4 + r;
                int gc = n0 + wn + ni * 16 + tl;
                long long idx = (long long)gr * ldc + gc;
                float v = acc[mi][ni][r];
                if (MODE == 0) {
                    ((bf16_t*)Cv)[idx] = (bf16_t)v;
                } else if (MODE == 1) {
                    ((float*)Cv)[idx] = ((const float*)aux)[idx] + v;
                } else {
                    float g = (float)((const bf16_t*)aux)[idx];
                    float t = 0.7978845608028654f * (g + 0.044715f * g * g * g);
                    float ge = 0.5f * g * (1.0f + tanhf(t));
                    ((bf16_t*)Cv)[idx] = (bf16_t)(ge * v);
                }
            }
        }
    }
}

// ---------------- launch ----------------
extern "C" void kernel_launch(void* const* d_in, const int* in_sizes, int n_in,
                              void* d_out, int out_size, void* d_ws, size_t ws_size,
                              hipStream_t stream) {
    const float* hidden = (const float*)d_in[0];
    const float* q_w    = (const float*)d_in[1];
    const float* k_w    = (const float*)d_in[2];
    const float* v_w    = (const float*)d_in[3];
    const float* o_w    = (const float*)d_in[4];
    const float* gate_w = (const float*)d_in[5];
    const float* up_w   = (const float*)d_in[6];
    const float* down_w = (const float*)d_in[7];
    const float* ln1_w  = (const float*)d_in[8];
    const float* ln2_w  = (const float*)d_in[9];
    const int* amask    = (const int*)d_in[10];
    const int* pos_ids  = (const int*)d_in[11];
    float* out = (float*)d_out;

    // ---- workspace layout, time-shared (peak 192 MiB) ----
    // phase A: wq/wk/wv/wo 0..24 | xb 24..40 | qb 40..56 kb 56..64 vb 64..72 vT 72..80
    // phase B: op[0..3] 80..144 | mlb 144..145
    // phase C: attnb 24..40 (over dead xb) | xb2 48..64 (over dead qb/kb)
    // phase D: wgT 64..96, wuT 96..128, wdT 128..160 (over dead vb/vT/op/mlb)
    //          gb 160..192 (FFN half-chunk)
    const size_t MB = 1ull << 20;
    char* ws = (char*)d_ws;
    bf16_t* wqT   = (bf16_t*)(ws + 0 * MB);
    bf16_t* wkT   = (bf16_t*)(ws + 8 * MB);
    bf16_t* wvT   = (bf16_t*)(ws + 12 * MB);
    bf16_t* woT   = (bf16_t*)(ws + 16 * MB);
    bf16_t* xb    = (bf16_t*)(ws + 24 * MB);
    bf16_t* qb    = (bf16_t*)(ws + 40 * MB);
    bf16_t* kb    = (bf16_t*)(ws + 56 * MB);
    bf16_t* vb    = (bf16_t*)(ws + 64 * MB);
    bf16_t* vT    = (bf16_t*)(ws + 72 * MB);
    bf16_t* opb   = (bf16_t*)(ws + 80 * MB);   // 4 x 16 MiB partials
    float*  mlb   = (float*) (ws + 144 * MB);  // 1 MiB
    bf16_t* attnb = (bf16_t*)(ws + 24 * MB);
    bf16_t* xb2   = (bf16_t*)(ws + 48 * MB);
    bf16_t* wgT   = (bf16_t*)(ws + 64 * MB);
    bf16_t* wuT   = (bf16_t*)(ws + 96 * MB);
    bf16_t* wdT   = (bf16_t*)(ws + 128 * MB);
    bf16_t* gb    = (bf16_t*)(ws + 160 * MB);  // [4096][4096] half-FFN buffer
    (void)ws_size; (void)in_sizes; (void)n_in; (void)out_size;

    dim3 blk(256);

    // attention-side weight transposes
    transpose_bf16_kernel<float><<<dim3(64, 64), blk, 0, stream>>>(q_w, wqT, 2048, 2048);
    transpose_bf16_kernel<float><<<dim3(32, 64), blk, 0, stream>>>(k_w, wkT, 2048, 1024);
    transpose_bf16_kernel<float><<<dim3(32, 64), blk, 0, stream>>>(v_w, wvT, 2048, 1024);
    transpose_bf16_kernel<float><<<dim3(64, 64), blk, 0, stream>>>(o_w, woT, 2048, 2048);

    // RMSNorm 1
    rmsnorm_kernel<<<dim3(S_LEN), blk, 0, stream>>>(hidden, ln1_w, xb);

    // QKV projections
    gemm_kernel<0><<<dim3(16, 32), blk, 0, stream>>>(xb, HID, wqT, HID, qb, 2048, nullptr, HID);
    gemm_kernel<0><<<dim3(8, 32), blk, 0, stream>>>(xb, HID, wkT, HID, kb, 1024, nullptr, HID);
    gemm_kernel<0><<<dim3(8, 32), blk, 0, stream>>>(xb, HID, wvT, HID, vb, 1024, nullptr, HID);

    // RoPE
    rope_kernel<<<dim3(S_LEN), blk, 0, stream>>>(qb, kb, pos_ids);

    // v^T for flash PV
    transpose_bf16_kernel<bf16_t><<<dim3(32, 128), blk, 0, stream>>>(vb, vT, S_LEN, 1024);

    // flash attention (paired q-tiles, 4 k-quarters) -> opb/mlb, then combine
    flash_attn_kernel<<<dim3(16, NHEADS, 4), blk, 0, stream>>>(qb, kb, vT, opb, mlb, amask);
    combine_kernel<<<dim3(NHEADS, S_LEN), blk, 0, stream>>>(opb, mlb, attnb);

    // O projection + residual into d_out (fp32)
    gemm_kernel<1><<<dim3(16, 32), blk, 0, stream>>>(attnb, 2048, woT, 2048, out, 2048, hidden, 2048);

    // RMSNorm 2
    rmsnorm_kernel<<<dim3(S_LEN), blk, 0, stream>>>(out, ln2_w, xb2);

    // MLP-side weight transposes (deferred; reuse dead attention space)
    transpose_bf16_kernel<float><<<dim3(256, 64), blk, 0, stream>>>(gate_w, wgT, 2048, 8192);
    transpose_bf16_kernel<float><<<dim3(256, 64), blk, 0, stream>>>(up_w, wuT, 2048, 8192);
    transpose_bf16_kernel<float><<<dim3(64, 256), blk, 0, stream>>>(down_w, wdT, 8192, 2048);

    // MLP in two FFN-half chunks: gate -> gb, up (gelu*up in-place), down (+= into out)
    for (int c = 0; c < 2; ++c) {
        bf16_t* wgc = wgT + (size_t)c * 4096 * HID;
        bf16_t* wuc = wuT + (size_t)c * 4096 * HID;
        bf16_t* wdc = wdT + (size_t)c * 4096;
        gemm_kernel<0><<<dim3(32, 32), blk, 0, stream>>>(xb2, HID, wgc, HID, gb, 4096, nullptr, HID);
        gemm_kernel<2><<<dim3(32, 32), blk, 0, stream>>>(xb2, HID, wuc, HID, gb, 4096, gb, HID);
        gemm_kernel<1><<<dim3(16, 32), blk, 0, stream>>>(gb, 4096, wdc, FFN, out, 2048, out, 4096);
    }
}

// Round 5
// 1393.319 us; speedup vs baseline: 1.2006x; 1.2006x over previous
//
#include <hip/hip_runtime.h>
#include <hip/hip_bf16.h>
#include <math.h>

#define S_LEN 4096
#define HID   2048
#define NHEADS 8
#define NKVH   4
#define HDIM   256
#define FFN    8192
#define WIN    4096

typedef __bf16 bf16_t;
typedef __bf16 bf16x4 __attribute__((ext_vector_type(4)));
typedef __bf16 bf16x8 __attribute__((ext_vector_type(8)));
typedef float  floatx4 __attribute__((ext_vector_type(4)));

// ---------------- reduction helpers (256-thread blocks, 4 waves) ----------------
__device__ inline float waveReduceSum(float v) {
#pragma unroll
    for (int o = 32; o > 0; o >>= 1) v += __shfl_xor(v, o);
    return v;
}
__device__ inline float blockReduceSum(float v, float* sh) {
    int tid = threadIdx.x;
    v = waveReduceSum(v);
    if ((tid & 63) == 0) sh[tid >> 6] = v;
    __syncthreads();
    v = sh[0] + sh[1] + sh[2] + sh[3];
    __syncthreads();
    return v;
}

// ---------------- transpose + cast to bf16: in[R][C] -> out[C][R] ----------------
template <typename T>
__global__ __launch_bounds__(256) void transpose_bf16_kernel(const T* __restrict__ in,
                                                             bf16_t* __restrict__ out,
                                                             int R, int C) {
    __shared__ float tile[32][33];
    int tx = threadIdx.x & 31;
    int ty = threadIdx.x >> 5;  // 0..7
    int c0 = blockIdx.x * 32;
    int r0 = blockIdx.y * 32;
#pragma unroll
    for (int i = 0; i < 4; ++i)
        tile[ty + i * 8][tx] = (float)in[(long long)(r0 + ty + i * 8) * C + c0 + tx];
    __syncthreads();
#pragma unroll
    for (int i = 0; i < 4; ++i)
        out[(long long)(c0 + ty + i * 8) * R + r0 + tx] = (bf16_t)tile[tx][ty + i * 8];
}

// ---------------- RMSNorm (fp32 in -> bf16 out), one row per block ----------------
__global__ __launch_bounds__(256) void rmsnorm_kernel(const float* __restrict__ x,
                                                      const float* __restrict__ w,
                                                      bf16_t* __restrict__ out) {
    __shared__ float sh[4];
    int row = blockIdx.x;
    const float* xr = x + (long long)row * HID;
    float v[8];
    float ss = 0.f;
#pragma unroll
    for (int i = 0; i < 8; ++i) {
        v[i] = xr[threadIdx.x + i * 256];
        ss += v[i] * v[i];
    }
    ss = blockReduceSum(ss, sh);
    float sc = rsqrtf(ss * (1.0f / HID) + 1e-6f);
#pragma unroll
    for (int i = 0; i < 8; ++i) {
        int c = threadIdx.x + i * 256;
        out[(long long)row * HID + c] = (bf16_t)(v[i] * sc * w[c]);
    }
}

// ---------------- RoPE in-place on bf16 q [S,NH*HD] and k [S,NKV*HD] ----------------
__global__ __launch_bounds__(256) void rope_kernel(bf16_t* __restrict__ q,
                                                   bf16_t* __restrict__ k,
                                                   const int* __restrict__ pos_ids) {
    int s = blockIdx.x;
    float p = (float)pos_ids[s];
    for (int t = threadIdx.x; t < (NHEADS + NKVH) * (HDIM / 2); t += 256) {
        int head = t >> 7;        // 0..11
        int i = t & 127;          // rotary pair index
        float inv = expf(-(2.0f * (float)i / (float)HDIM) * 9.210340371976184f);  // theta^-2i/HD
        float f = p * inv;
        float sn, cs;
        sincosf(f, &sn, &cs);
        bf16_t* base = (head < NHEADS) ? (q + (long long)s * HID + head * HDIM)
                                       : (k + (long long)s * (NKVH * HDIM) + (head - NHEADS) * HDIM);
        float a = (float)base[i];
        float b = (float)base[i + 128];
        base[i]       = (bf16_t)(a * cs - b * sn);
        base[i + 128] = (bf16_t)(b * cs + a * sn);
    }
}

// ---------------- flash attention v5 ----------------
// 1-D grid of 512 blocks, XCD-swizzled: h = b&7 (blockIdx%8 -> XCD heuristic puts
// one q-head per XCD; its K/V working set = 4 MiB = one XCD L2). j = b>>3:
// quarter = j&3, pair index = j>>2 -> q-tiles {x, 31-x} of 128 rows.
// Wave owns 32 queries (2 sets of 16); every K/V fragment feeds 2 MFMAs.
// Fragment-ordered LDS (lane-linear ds_read_b128). Keys split across 4 quarters;
// normalized partial O + (m,l) per quarter, combined after.
__global__ __launch_bounds__(256, 2) void flash_attn_kernel(const bf16_t* __restrict__ qg,
                                                            const bf16_t* __restrict__ kg,
                                                            const bf16_t* __restrict__ vTg,
                                                            bf16_t* __restrict__ op0,
                                                            bf16_t* __restrict__ opb123,
                                                            float* __restrict__ mlb,
                                                            const int* __restrict__ amask) {
    __shared__ bf16_t sK[64 * 256];   // 32 KiB, 32 frags (f=ks*4+ni): lane(tl,q) = K[(f&3)*16+tl][dchunk=(f>>2)*4+q]
    __shared__ bf16_t sV[256 * 64];   // 32 KiB, 32 frags (f=k2*16+dt): lane(tl,q) = V^T[(f&15)*16+tl][kchunk=(f>>4)*4+q]

    const int b = blockIdx.x;
    const int h = b & 7;              // XCD-aligned head
    const int j = b >> 3;
    const int jq = j & 3;             // k-quarter
    const int pidx = j >> 2;          // pair 0..15
    const int tid = threadIdx.x;
    const int lane = tid & 63;
    const int w = tid >> 6;
    const int tl = lane & 15;
    const int quad = lane >> 4;

    const bf16_t* Qh = qg + h * HDIM;
    const bf16_t* Kh = kg + (h >> 1) * HDIM;
    const bf16_t* Vh = vTg + (long long)(h >> 1) * HDIM * S_LEN;
    bf16_t* Op = (jq == 0) ? op0 : opb123 + (long long)(jq - 1) * (S_LEN * HID);
    float* mlj = mlb + (long long)jq * (NHEADS * S_LEN * 2);
    bf16_t* sP = sK + w * (32 * 72);  // per-wave P [32 q][64 k], stride 72, aliases dead sK

#pragma unroll 1
    for (int half = 0; half < 2; ++half) {
        const int qi = half ? (31 - pidx) : pidx;
        const int qr0 = qi * 128;
        const int T = 2 * qi + 2;
        const int t0 = (T * jq) >> 2;
        const int t1 = (T * (jq + 1)) >> 2;
        const int irow = qr0 + w * 32 + tl;  // set-0 query row; set 1 = +16

        // Q fragments (B-operand: n=tl=query, k=quad*8+j within 32-slice ks)
        bf16x8 qf[2][8];
#pragma unroll
        for (int s = 0; s < 2; ++s) {
            const bf16_t* qrow = Qh + (long long)(irow + s * 16) * HID;
#pragma unroll
            for (int ks = 0; ks < 8; ++ks)
                qf[s][ks] = *(const bf16x8*)(qrow + (ks * 4 + quad) * 8);
        }

        floatx4 oacc[2][16] = {};
        float m_i[2] = {-3e38f, -3e38f};
        float l_i[2] = {0.f, 0.f};

        for (int t = t0; t < t1; ++t) {
            const int kt = t * 64;
            // ---- stage K & V^T tiles, fragment-ordered, 16B/lane ----
#pragma unroll
            for (int it = 0; it < 8; ++it) {
                int f = it * 4 + w;
                {
                    int row = (f & 3) * 16 + tl;
                    int dc = (f >> 2) * 4 + quad;
                    const bf16_t* src = Kh + (long long)(kt + row) * (NKVH * HDIM) + dc * 8;
                    __builtin_amdgcn_global_load_lds((const __attribute__((address_space(1))) void*)src,
                                                     (__attribute__((address_space(3))) void*)(sK + (it * 256 + tid) * 8),
                                                     16, 0, 0);
                }
                {
                    int d = (f & 15) * 16 + tl;
                    int kc = (f >> 4) * 4 + quad;
                    const bf16_t* src = Vh + (long long)d * S_LEN + kt + kc * 8;
                    __builtin_amdgcn_global_load_lds((const __attribute__((address_space(1))) void*)src,
                                                     (__attribute__((address_space(3))) void*)(sV + (it * 256 + tid) * 8),
                                                     16, 0, 0);
                }
            }
            __builtin_amdgcn_s_waitcnt(0x0f70);  // vmcnt(0)
            __syncthreads();

            // ---- S^T = K Q^T : lane holds S[q=tl(set)][key=kt+ni*16+quad*4+r] ----
            floatx4 sacc[2][4] = {};
#pragma unroll
            for (int ks = 0; ks < 8; ++ks) {
#pragma unroll
                for (int ni = 0; ni < 4; ++ni) {
                    bf16x8 kf = *(const bf16x8*)(sK + ((ks * 4 + ni) * 64 + lane) * 8);
                    sacc[0][ni] = __builtin_amdgcn_mfma_f32_16x16x32_bf16(kf, qf[0][ks], sacc[0][ni], 0, 0, 0);
                    sacc[1][ni] = __builtin_amdgcn_mfma_f32_16x16x32_bf16(kf, qf[1][ks], sacc[1][ni], 0, 0, 0);
                }
            }
            __syncthreads();  // all waves done with sK; sP (alias) writable

            // ---- online softmax per set ----
            int4 am4[4];
#pragma unroll
            for (int ni = 0; ni < 4; ++ni) am4[ni] = *(const int4*)(amask + kt + ni * 16 + quad * 4);
#pragma unroll
            for (int s = 0; s < 2; ++s) {
                const int ir = irow + s * 16;
                float sv[4][4];
                float mx = -3e38f;
#pragma unroll
                for (int ni = 0; ni < 4; ++ni) {
#pragma unroll
                    for (int r = 0; r < 4; ++r) {
                        int jk = kt + ni * 16 + quad * 4 + r;
                        int amr = (r == 0) ? am4[ni].x : (r == 1) ? am4[ni].y : (r == 2) ? am4[ni].z : am4[ni].w;
                        bool valid = (jk <= ir) && (jk > ir - WIN) && (amr > 0);
                        float x = valid ? sacc[s][ni][r] * 0.0625f : -3e38f;
                        sv[ni][r] = x;
                        mx = fmaxf(mx, x);
                    }
                }
                mx = fmaxf(mx, __shfl_xor(mx, 16));
                mx = fmaxf(mx, __shfl_xor(mx, 32));
                if (__any(mx > m_i[s])) {       // rescale only when any query's max moved
                    float mnew = fmaxf(m_i[s], mx);
                    float alpha = __expf(m_i[s] - mnew);
                    m_i[s] = mnew;
                    l_i[s] *= alpha;
                    floatx4 av;
#pragma unroll
                    for (int r = 0; r < 4; ++r) av[r] = __shfl(alpha, quad * 4 + r);
#pragma unroll
                    for (int dt = 0; dt < 16; ++dt) oacc[s][dt] *= av;
                }
                float rs = 0.f;
#pragma unroll
                for (int ni = 0; ni < 4; ++ni) {
                    bf16x4 pk;
#pragma unroll
                    for (int r = 0; r < 4; ++r) {
                        float p = (sv[ni][r] > -1e37f) ? __expf(sv[ni][r] - m_i[s]) : 0.f;
                        rs += p;
                        pk[r] = (bf16_t)p;
                    }
                    *(bf16x4*)(sP + (s * 16 + tl) * 72 + ni * 16 + quad * 4) = pk;
                }
                rs += __shfl_xor(rs, 16);
                rs += __shfl_xor(rs, 32);
                l_i[s] += rs;
            }

            // ---- O += P V : vf read once, feeds both q-sets ----
#pragma unroll
            for (int k2 = 0; k2 < 2; ++k2) {
                bf16x8 pf0 = *(const bf16x8*)(sP + tl * 72 + k2 * 32 + quad * 8);
                bf16x8 pf1 = *(const bf16x8*)(sP + (16 + tl) * 72 + k2 * 32 + quad * 8);
#pragma unroll
                for (int dt = 0; dt < 16; ++dt) {
                    bf16x8 vf = *(const bf16x8*)(sV + ((k2 * 16 + dt) * 64 + lane) * 8);
                    oacc[0][dt] = __builtin_amdgcn_mfma_f32_16x16x32_bf16(pf0, vf, oacc[0][dt], 0, 0, 0);
                    oacc[1][dt] = __builtin_amdgcn_mfma_f32_16x16x32_bf16(pf1, vf, oacc[1][dt], 0, 0, 0);
                }
            }
            __syncthreads();  // protect sK/sV/sP before next staging
        }

        // ---- epilogue: normalized partial O + (m,l) ----
#pragma unroll
        for (int s = 0; s < 2; ++s) {
            floatx4 inv;
#pragma unroll
            for (int r = 0; r < 4; ++r) {
                float lv = __shfl(l_i[s], quad * 4 + r);
                inv[r] = (lv > 0.f) ? 1.0f / lv : 0.f;
            }
#pragma unroll
            for (int dt = 0; dt < 16; ++dt) {
#pragma unroll
                for (int r = 0; r < 4; ++r) {
                    long long row = qr0 + w * 32 + s * 16 + quad * 4 + r;
                    Op[row * HID + h * HDIM + dt * 16 + tl] = (bf16_t)(oacc[s][dt][r] * inv[r]);
                }
            }
            if (quad == 0) {
                long long mi2 = ((long long)h * S_LEN + irow + s * 16) * 2;
                mlj[mi2] = m_i[s];
                mlj[mi2 + 1] = l_i[s];
            }
        }
    }
}

// ---------------- combine 4 k-quarter partials -> attnb ----------------
__global__ __launch_bounds__(256) void combine_kernel(const bf16_t* __restrict__ op0,
                                                      const bf16_t* __restrict__ opb123,
                                                      const float* __restrict__ mlb,
                                                      bf16_t* __restrict__ attnb) {
    int h = blockIdx.x;
    int row = blockIdx.y;
    int d = threadIdx.x;
    float m[4], l[4];
    float M = -3e38f;
#pragma unroll
    for (int j = 0; j < 4; ++j) {
        long long mi = (((long long)j * NHEADS + h) * S_LEN + row) * 2;
        m[j] = mlb[mi];
        l[j] = mlb[mi + 1];
        M = fmaxf(M, m[j]);
    }
    float wj[4], wsum = 0.f;
#pragma unroll
    for (int j = 0; j < 4; ++j) {
        wj[j] = (l[j] > 0.f) ? l[j] * __expf(m[j] - M) : 0.f;
        wsum += wj[j];
    }
    float inv = 1.0f / wsum;
    long long idx = (long long)row * HID + h * HDIM + d;
    float acc = wj[0] * (float)op0[idx];
#pragma unroll
    for (int j = 1; j < 4; ++j)
        acc += wj[j] * (float)opb123[(long long)(j - 1) * (S_LEN * HID) + idx];
    attnb[idx] = (bf16_t)(acc * inv);
}

// ---------------- MFMA GEMM: C[M,N] = A[M,K] * Bt[N,K]^T (round-3 proven) ----------------
// 128x128 tile, BK=64, 256 threads (2x2 waves of 64x64), global_load_lds staging,
// XOR-swizzled LDS chunk layout (row-dense 128B global segments).
// MODE: 0 = store bf16; 1 = fp32 store of aux+acc; 2 = bf16 store of gelu(aux)*acc.
template <int MODE>
__global__ __launch_bounds__(256) void gemm_kernel(const bf16_t* __restrict__ A, int lda,
                                                   const bf16_t* __restrict__ Bt, int ldb,
                                                   void* __restrict__ Cv, int ldc,
                                                   const void* __restrict__ aux, int K) {
    __shared__ bf16_t smem[2 * 128 * 64];
    bf16_t* sA = smem;
    bf16_t* sB = smem + 128 * 64;

    const int tid = threadIdx.x;
    const int n0 = blockIdx.x * 128;
    const int m0 = blockIdx.y * 128;

    const int lane = tid & 63;
    const int wid = tid >> 6;
    const int wm = (wid >> 1) * 64;
    const int wn = (wid & 1) * 64;
    const int tl = lane & 15;
    const int quad = lane >> 4;

    floatx4 acc[4][4] = {};

    for (int k0 = 0; k0 < K; k0 += 64) {
#pragma unroll
        for (int it = 0; it < 4; ++it) {
            int s = it * 256 + tid;      // 16B slot index 0..1023
            int m = s >> 3;              // tile row 0..127
            int sg = s & 7;              // stored chunk within row
            int g = sg ^ (m & 7);        // source chunk (XOR swizzle, self-inverse)
            const bf16_t* ga = A + (long long)(m0 + m) * lda + k0 + g * 8;
            __builtin_amdgcn_global_load_lds((const __attribute__((address_space(1))) void*)ga,
                                             (__attribute__((address_space(3))) void*)(sA + s * 8),
                                             16, 0, 0);
            const bf16_t* gb = Bt + (long long)(n0 + m) * ldb + k0 + g * 8;
            __builtin_amdgcn_global_load_lds((const __attribute__((address_space(1))) void*)gb,
                                             (__attribute__((address_space(3))) void*)(sB + s * 8),
                                             16, 0, 0);
        }
        __builtin_amdgcn_s_waitcnt(0x0f70);  // vmcnt(0)
        __syncthreads();

#pragma unroll
        for (int kk = 0; kk < 2; ++kk) {
            bf16x8 af[4], bfr[4];
#pragma unroll
            for (int mi = 0; mi < 4; ++mi) {
                int m = wm + mi * 16 + tl;
                int sg = (kk * 4 + quad) ^ (m & 7);
                af[mi] = *(const bf16x8*)(sA + m * 64 + sg * 8);
            }
#pragma unroll
            for (int ni = 0; ni < 4; ++ni) {
                int n = wn + ni * 16 + tl;
                int sg = (kk * 4 + quad) ^ (n & 7);
                bfr[ni] = *(const bf16x8*)(sB + n * 64 + sg * 8);
            }
#pragma unroll
            for (int mi = 0; mi < 4; ++mi)
#pragma unroll
                for (int ni = 0; ni < 4; ++ni)
                    acc[mi][ni] = __builtin_amdgcn_mfma_f32_16x16x32_bf16(af[mi], bfr[ni], acc[mi][ni], 0, 0, 0);
        }
        __syncthreads();
    }

    // epilogue: C/D layout col=lane&15, row=quad*4+r
#pragma unroll
    for (int mi = 0; mi < 4; ++mi) {
#pragma unroll
        for (int ni = 0; ni < 4; ++ni) {
#pragma unroll
            for (int r = 0; r < 4; ++r) {
                int gr = m0 + wm + mi * 16 + quad * 4 + r;
                int gc = n0 + wn + ni * 16 + tl;
                long long idx = (long long)gr * ldc + gc;
                float v = acc[mi][ni][r];
                if (MODE == 0) {
                    ((bf16_t*)Cv)[idx] = (bf16_t)v;
                } else if (MODE == 1) {
                    ((float*)Cv)[idx] = ((const float*)aux)[idx] + v;
                } else {
                    float g = (float)((const bf16_t*)aux)[idx];
                    float t = 0.7978845608028654f * (g + 0.044715f * g * g * g);
                    float ge = 0.5f * g * (1.0f + tanhf(t));
                    ((bf16_t*)Cv)[idx] = (bf16_t)(ge * v);
                }
            }
        }
    }
}

// ---------------- launch ----------------
extern "C" void kernel_launch(void* const* d_in, const int* in_sizes, int n_in,
                              void* d_out, int out_size, void* d_ws, size_t ws_size,
                              hipStream_t stream) {
    const float* hidden = (const float*)d_in[0];
    const float* q_w    = (const float*)d_in[1];
    const float* k_w    = (const float*)d_in[2];
    const float* v_w    = (const float*)d_in[3];
    const float* o_w    = (const float*)d_in[4];
    const float* gate_w = (const float*)d_in[5];
    const float* up_w   = (const float*)d_in[6];
    const float* down_w = (const float*)d_in[7];
    const float* ln1_w  = (const float*)d_in[8];
    const float* ln2_w  = (const float*)d_in[9];
    const int* amask    = (const int*)d_in[10];
    const int* pos_ids  = (const int*)d_in[11];
    float* out = (float*)d_out;

    // ---- workspace layout, time-shared (peak 193 MiB) ----
    // wq 0..8 | wk 8..12 | wv 12..16 | wo 16..24 | wgT 24..56 | wuT 56..88 |
    // xb 88..104 (-> op0) | qb 104..120 (-> attnb, then part of gb) |
    // kb 120..128, vb 128..136 (-> xb2) | vT 136..144 (-> wdT 144..176 over op1/op2) |
    // op1/2/3 144..192 | mlb 192..193 | gb 88..120 (post o-proj)
    const size_t MB = 1ull << 20;
    char* ws = (char*)d_ws;
    bf16_t* wqT    = (bf16_t*)(ws + 0 * MB);
    bf16_t* wkT    = (bf16_t*)(ws + 8 * MB);
    bf16_t* wvT    = (bf16_t*)(ws + 12 * MB);
    bf16_t* woT    = (bf16_t*)(ws + 16 * MB);
    bf16_t* wgT    = (bf16_t*)(ws + 24 * MB);
    bf16_t* wuT    = (bf16_t*)(ws + 56 * MB);
    bf16_t* xb     = (bf16_t*)(ws + 88 * MB);
    bf16_t* qb     = (bf16_t*)(ws + 104 * MB);
    bf16_t* kb     = (bf16_t*)(ws + 120 * MB);
    bf16_t* vb     = (bf16_t*)(ws + 128 * MB);
    bf16_t* vT     = (bf16_t*)(ws + 136 * MB);
    bf16_t* op0    = (bf16_t*)(ws + 88 * MB);   // over dead xb
    bf16_t* opb123 = (bf16_t*)(ws + 144 * MB);  // 3 x 16 MiB
    float*  mlb    = (float*) (ws + 192 * MB);  // 1 MiB
    bf16_t* attnb  = (bf16_t*)(ws + 104 * MB);  // over dead qb
    bf16_t* xb2    = (bf16_t*)(ws + 120 * MB);  // over dead kb+vb
    bf16_t* wdT    = (bf16_t*)(ws + 144 * MB);  // over dead vT.. wait: 144..176 over op1/op2 (dead post-combine)
    bf16_t* gb     = (bf16_t*)(ws + 88 * MB);   // 32 MiB [4096][4096], over dead op0+attnb
    (void)ws_size; (void)in_sizes; (void)n_in; (void)out_size;

    dim3 blk(256);

    // weight transposes (attention + gate/up); down_w deferred
    transpose_bf16_kernel<float><<<dim3(64, 64), blk, 0, stream>>>(q_w, wqT, 2048, 2048);
    transpose_bf16_kernel<float><<<dim3(32, 64), blk, 0, stream>>>(k_w, wkT, 2048, 1024);
    transpose_bf16_kernel<float><<<dim3(32, 64), blk, 0, stream>>>(v_w, wvT, 2048, 1024);
    transpose_bf16_kernel<float><<<dim3(64, 64), blk, 0, stream>>>(o_w, woT, 2048, 2048);
    transpose_bf16_kernel<float><<<dim3(256, 64), blk, 0, stream>>>(gate_w, wgT, 2048, 8192);
    transpose_bf16_kernel<float><<<dim3(256, 64), blk, 0, stream>>>(up_w, wuT, 2048, 8192);

    // RMSNorm 1
    rmsnorm_kernel<<<dim3(S_LEN), blk, 0, stream>>>(hidden, ln1_w, xb);

    // QKV projections
    gemm_kernel<0><<<dim3(16, 32), blk, 0, stream>>>(xb, HID, wqT, HID, qb, 2048, nullptr, HID);
    gemm_kernel<0><<<dim3(8, 32), blk, 0, stream>>>(xb, HID, wkT, HID, kb, 1024, nullptr, HID);
    gemm_kernel<0><<<dim3(8, 32), blk, 0, stream>>>(xb, HID, wvT, HID, vb, 1024, nullptr, HID);

    // RoPE
    rope_kernel<<<dim3(S_LEN), blk, 0, stream>>>(qb, kb, pos_ids);

    // v^T for flash PV
    transpose_bf16_kernel<bf16_t><<<dim3(32, 128), blk, 0, stream>>>(vb, vT, S_LEN, 1024);

    // flash attention (XCD-swizzled 1-D grid) -> partials, then combine
    flash_attn_kernel<<<dim3(512), blk, 0, stream>>>(qb, kb, vT, op0, opb123, mlb, amask);
    combine_kernel<<<dim3(NHEADS, S_LEN), blk, 0, stream>>>(op0, opb123, mlb, attnb);

    // O projection + residual into d_out (fp32)
    gemm_kernel<1><<<dim3(16, 32), blk, 0, stream>>>(attnb, 2048, woT, 2048, out, 2048, hidden, 2048);

    // RMSNorm 2
    rmsnorm_kernel<<<dim3(S_LEN), blk, 0, stream>>>(out, ln2_w, xb2);

    // down_w transpose into dead partial space
    transpose_bf16_kernel<float><<<dim3(64, 256), blk, 0, stream>>>(down_w, wdT, 8192, 2048);

    // MLP in two FFN-half chunks: gate -> gb, up (gelu*up in-place), down (+= into out)
    for (int c = 0; c < 2; ++c) {
        bf16_t* wgc = wgT + (size_t)c * 4096 * HID;
        bf16_t* wuc = wuT + (size_t)c * 4096 * HID;
        bf16_t* wdc = wdT + (size_t)c * 4096;
        gemm_kernel<0><<<dim3(32, 32), blk, 0, stream>>>(xb2, HID, wgc, HID, gb, 4096, nullptr, HID);
        gemm_kernel<2><<<dim3(32, 32), blk, 0, stream>>>(xb2, HID, wuc, HID, gb, 4096, gb, HID);
        gemm_kernel<1><<<dim3(16, 32), blk, 0, stream>>>(gb, 4096, wdc, FFN, out, 2048, out, 4096);
    }
}

// Round 6
// 1354.121 us; speedup vs baseline: 1.2353x; 1.0289x over previous
//
#include <hip/hip_runtime.h>
#include <hip/hip_bf16.h>
#include <math.h>

#define S_LEN 4096
#define HID   2048
#define NHEADS 8
#define NKVH   4
#define HDIM   256
#define FFN    8192
#define WIN    4096

typedef __bf16 bf16_t;
typedef __bf16 bf16x4 __attribute__((ext_vector_type(4)));
typedef __bf16 bf16x8 __attribute__((ext_vector_type(8)));
typedef float  floatx4 __attribute__((ext_vector_type(4)));

// ---------------- reduction helpers (256-thread blocks, 4 waves) ----------------
__device__ inline float waveReduceSum(float v) {
#pragma unroll
    for (int o = 32; o > 0; o >>= 1) v += __shfl_xor(v, o);
    return v;
}
__device__ inline float blockReduceSum(float v, float* sh) {
    int tid = threadIdx.x;
    v = waveReduceSum(v);
    if ((tid & 63) == 0) sh[tid >> 6] = v;
    __syncthreads();
    v = sh[0] + sh[1] + sh[2] + sh[3];
    __syncthreads();
    return v;
}

// ---------------- transpose + cast to bf16: in[R][C] -> out[C][R] ----------------
template <typename T>
__global__ __launch_bounds__(256) void transpose_bf16_kernel(const T* __restrict__ in,
                                                             bf16_t* __restrict__ out,
                                                             int R, int C) {
    __shared__ float tile[32][33];
    int tx = threadIdx.x & 31;
    int ty = threadIdx.x >> 5;  // 0..7
    int c0 = blockIdx.x * 32;
    int r0 = blockIdx.y * 32;
#pragma unroll
    for (int i = 0; i < 4; ++i)
        tile[ty + i * 8][tx] = (float)in[(long long)(r0 + ty + i * 8) * C + c0 + tx];
    __syncthreads();
#pragma unroll
    for (int i = 0; i < 4; ++i)
        out[(long long)(c0 + ty + i * 8) * R + r0 + tx] = (bf16_t)tile[tx][ty + i * 8];
}

// ---------------- RMSNorm (fp32 in -> bf16 out), one row per block ----------------
__global__ __launch_bounds__(256) void rmsnorm_kernel(const float* __restrict__ x,
                                                      const float* __restrict__ w,
                                                      bf16_t* __restrict__ out) {
    __shared__ float sh[4];
    int row = blockIdx.x;
    const float* xr = x + (long long)row * HID;
    float v[8];
    float ss = 0.f;
#pragma unroll
    for (int i = 0; i < 8; ++i) {
        v[i] = xr[threadIdx.x + i * 256];
        ss += v[i] * v[i];
    }
    ss = blockReduceSum(ss, sh);
    float sc = rsqrtf(ss * (1.0f / HID) + 1e-6f);
#pragma unroll
    for (int i = 0; i < 8; ++i) {
        int c = threadIdx.x + i * 256;
        out[(long long)row * HID + c] = (bf16_t)(v[i] * sc * w[c]);
    }
}

// ---------------- RoPE in-place on bf16 q [S,NH*HD] and k [S,NKV*HD] ----------------
__global__ __launch_bounds__(256) void rope_kernel(bf16_t* __restrict__ q,
                                                   bf16_t* __restrict__ k,
                                                   const int* __restrict__ pos_ids) {
    int s = blockIdx.x;
    float p = (float)pos_ids[s];
    for (int t = threadIdx.x; t < (NHEADS + NKVH) * (HDIM / 2); t += 256) {
        int head = t >> 7;        // 0..11
        int i = t & 127;          // rotary pair index
        float inv = expf(-(2.0f * (float)i / (float)HDIM) * 9.210340371976184f);  // theta^-2i/HD
        float f = p * inv;
        float sn, cs;
        sincosf(f, &sn, &cs);
        bf16_t* base = (head < NHEADS) ? (q + (long long)s * HID + head * HDIM)
                                       : (k + (long long)s * (NKVH * HDIM) + (head - NHEADS) * HDIM);
        float a = (float)base[i];
        float b = (float)base[i + 128];
        base[i]       = (bf16_t)(a * cs - b * sn);
        base[i + 128] = (bf16_t)(b * cs + a * sn);
    }
}

// ---------------- flash attention v6: GQA-shared 8-wave blocks + staging overlap ----
// Grid (16 pairs, NKVH, 4 quarters) = 256 blocks x 512 threads (1 block/CU).
// Waves 0-3 -> q-head 2*kvh, waves 4-7 -> q-head 2*kvh+1; one staged K/V tile
// serves both heads (halves HBM demand vs per-q-head blocks). Q pre-scaled by 1/16.
// Pipeline per k-tile: issue K(t+1)+V(t) staging, run QK(t) from sK[cur] (staging
// flies under it), __syncthreads (drain), softmax+P, PV, __syncthreads.
// sK double-buffered (2x32K), sV single (32K), P dedicated (36K): 132 KiB LDS.
__global__ __launch_bounds__(512, 1) void flash_attn_kernel(const bf16_t* __restrict__ qg,
                                                            const bf16_t* __restrict__ kg,
                                                            const bf16_t* __restrict__ vTg,
                                                            bf16_t* __restrict__ op0,
                                                            bf16_t* __restrict__ opb123,
                                                            float* __restrict__ mlb,
                                                            const int* __restrict__ amask) {
    __shared__ bf16_t sK[2][64 * 256];   // [key][d] fragment-ordered, 2x32 KiB
    __shared__ bf16_t sV[64 * 256];      // [d][key] fragment-ordered, 32 KiB
    __shared__ bf16_t sPB[8 * 32 * 72];  // per-wave P [32 q][64 k] stride 72, 36 KiB

    const int kvh = blockIdx.y;
    const int jq = blockIdx.z;
    const int tid = threadIdx.x;
    const int lane = tid & 63;
    const int w = tid >> 6;        // 0..7
    const int wq = w & 3;          // q-subtile within the 128-row q-block
    const int tl = lane & 15;
    const int quad = lane >> 4;
    const int h = kvh * 2 + (w >> 2);  // this wave's q-head

    const bf16_t* Qh = qg + h * HDIM;
    const bf16_t* Kh = kg + kvh * HDIM;
    const bf16_t* Vh = vTg + (long long)kvh * HDIM * S_LEN;
    bf16_t* Op = (jq == 0) ? op0 : opb123 + (long long)(jq - 1) * (S_LEN * HID);
    float* mlj = mlb + (long long)jq * (NHEADS * S_LEN * 2);
    bf16_t* sP = sPB + w * (32 * 72);

#pragma unroll 1
    for (int half = 0; half < 2; ++half) {
        const int qi = half ? (31 - blockIdx.x) : blockIdx.x;
        const int qr0 = qi * 128;
        const int T = 2 * qi + 2;
        const int t0 = (T * jq) >> 2;
        const int t1 = (T * (jq + 1)) >> 2;
        const int irow = qr0 + wq * 32 + tl;  // set-0 query row; set 1 = +16

        // Q fragments (B-operand: n=tl=query, k=quad*8+j within 32-slice ks)
        bf16x8 qf[2][8];
#pragma unroll
        for (int s = 0; s < 2; ++s) {
            const bf16_t* qrow = Qh + (long long)(irow + s * 16) * HID;
#pragma unroll
            for (int ks = 0; ks < 8; ++ks)
                qf[s][ks] = *(const bf16x8*)(qrow + (ks * 4 + quad) * 8);
        }

        floatx4 oacc[2][16] = {};
        float m_i[2] = {-3e38f, -3e38f};
        float l_i[2] = {0.f, 0.f};

        if (t0 < t1) {
            // prologue: stage K(t0)
#pragma unroll
            for (int it = 0; it < 4; ++it) {
                int f = it * 8 + w;
                const bf16_t* src = Kh + (long long)(t0 * 64 + (f & 3) * 16 + tl) * (NKVH * HDIM) + ((f >> 2) * 4 + quad) * 8;
                __builtin_amdgcn_global_load_lds((const __attribute__((address_space(1))) void*)src,
                                                 (__attribute__((address_space(3))) void*)(&sK[0][(it * 512 + tid) * 8]),
                                                 16, 0, 0);
            }
            __syncthreads();
            int cb = 0;
#pragma unroll 1
            for (int t = t0; t < t1; ++t) {
                const int kt = t * 64;
                // ---- issue V(t) staging + K(t+1) prefetch (fly under QK) ----
#pragma unroll
                for (int it = 0; it < 4; ++it) {
                    int f = it * 8 + w;
                    const bf16_t* src = Vh + (long long)((f & 15) * 16 + tl) * S_LEN + kt + ((f >> 4) * 4 + quad) * 8;
                    __builtin_amdgcn_global_load_lds((const __attribute__((address_space(1))) void*)src,
                                                     (__attribute__((address_space(3))) void*)(&sV[(it * 512 + tid) * 8]),
                                                     16, 0, 0);
                }
                if (t + 1 < t1) {
#pragma unroll
                    for (int it = 0; it < 4; ++it) {
                        int f = it * 8 + w;
                        const bf16_t* src = Kh + (long long)(kt + 64 + (f & 3) * 16 + tl) * (NKVH * HDIM) + ((f >> 2) * 4 + quad) * 8;
                        __builtin_amdgcn_global_load_lds((const __attribute__((address_space(1))) void*)src,
                                                         (__attribute__((address_space(3))) void*)(&sK[cb ^ 1][(it * 512 + tid) * 8]),
                                                         16, 0, 0);
                    }
                }

                // ---- S^T = K Q^T from sK[cb]; lane holds S[q=tl(set)][key=kt+ni*16+quad*4+r] ----
                const bf16_t* sKb = sK[cb];
                floatx4 sacc[2][4] = {};
#pragma unroll
                for (int ks = 0; ks < 8; ++ks) {
#pragma unroll
                    for (int ni = 0; ni < 4; ++ni) {
                        bf16x8 kf = *(const bf16x8*)(sKb + ((ks * 4 + ni) * 64 + lane) * 8);
                        sacc[0][ni] = __builtin_amdgcn_mfma_f32_16x16x32_bf16(kf, qf[0][ks], sacc[0][ni], 0, 0, 0);
                        sacc[1][ni] = __builtin_amdgcn_mfma_f32_16x16x32_bf16(kf, qf[1][ks], sacc[1][ni], 0, 0, 0);
                    }
                }
                __syncthreads();  // QK done block-wide; drains V(t) + K(t+1) staging

                // ---- online softmax per set (Q pre-scaled; keys in-lane + 2 shuffles) ----
                int4 am4[4];
#pragma unroll
                for (int ni = 0; ni < 4; ++ni) am4[ni] = *(const int4*)(amask + kt + ni * 16 + quad * 4);
                const bool full = (kt + 64 <= qr0);  // tile entirely below diagonal for all rows
#pragma unroll
                for (int s = 0; s < 2; ++s) {
                    const int ir = irow + s * 16;
                    float sv[4][4];
                    float mx = -3e38f;
#pragma unroll
                    for (int ni = 0; ni < 4; ++ni) {
#pragma unroll
                        for (int r = 0; r < 4; ++r) {
                            int amr = (r == 0) ? am4[ni].x : (r == 1) ? am4[ni].y : (r == 2) ? am4[ni].z : am4[ni].w;
                            bool valid = (amr > 0);
                            if (!full) {
                                int jk = kt + ni * 16 + quad * 4 + r;
                                valid = valid && (jk <= ir);
                            }
                            float x = valid ? sacc[s][ni][r] : -3e38f;
                            sv[ni][r] = x;
                            mx = fmaxf(mx, x);
                        }
                    }
                    mx = fmaxf(mx, __shfl_xor(mx, 16));
                    mx = fmaxf(mx, __shfl_xor(mx, 32));
                    if (__any(mx > m_i[s])) {  // rescale only when a query's max moved
                        float mnew = fmaxf(m_i[s], mx);
                        float alpha = __expf(m_i[s] - mnew);
                        m_i[s] = mnew;
                        l_i[s] *= alpha;
                        floatx4 av;
#pragma unroll
                        for (int r = 0; r < 4; ++r) av[r] = __shfl(alpha, quad * 4 + r);
#pragma unroll
                        for (int dt = 0; dt < 16; ++dt) oacc[s][dt] *= av;
                    }
                    float rs = 0.f;
#pragma unroll
                    for (int ni = 0; ni < 4; ++ni) {
                        bf16x4 pk;
#pragma unroll
                        for (int r = 0; r < 4; ++r) {
                            float p = (sv[ni][r] > -1e37f) ? __expf(sv[ni][r] - m_i[s]) : 0.f;
                            rs += p;
                            pk[r] = (bf16_t)p;
                        }
                        *(bf16x4*)(sP + (s * 16 + tl) * 72 + ni * 16 + quad * 4) = pk;
                    }
                    rs += __shfl_xor(rs, 16);
                    rs += __shfl_xor(rs, 32);
                    l_i[s] += rs;
                }

                // ---- O += P V : vf read once, feeds both q-sets ----
#pragma unroll
                for (int k2 = 0; k2 < 2; ++k2) {
                    bf16x8 pf0 = *(const bf16x8*)(sP + tl * 72 + k2 * 32 + quad * 8);
                    bf16x8 pf1 = *(const bf16x8*)(sP + (16 + tl) * 72 + k2 * 32 + quad * 8);
#pragma unroll
                    for (int dt = 0; dt < 16; ++dt) {
                        bf16x8 vf = *(const bf16x8*)(sV + ((k2 * 16 + dt) * 64 + lane) * 8);
                        oacc[0][dt] = __builtin_amdgcn_mfma_f32_16x16x32_bf16(pf0, vf, oacc[0][dt], 0, 0, 0);
                        oacc[1][dt] = __builtin_amdgcn_mfma_f32_16x16x32_bf16(pf1, vf, oacc[1][dt], 0, 0, 0);
                    }
                }
                __syncthreads();  // protect sV/sP/sK[cb] before next iteration's staging
                cb ^= 1;
            }
        }

        // ---- epilogue: normalized partial O + (m,l) ----
#pragma unroll
        for (int s = 0; s < 2; ++s) {
            floatx4 inv;
#pragma unroll
            for (int r = 0; r < 4; ++r) {
                float lv = __shfl(l_i[s], quad * 4 + r);
                inv[r] = (lv > 0.f) ? 1.0f / lv : 0.f;
            }
#pragma unroll
            for (int dt = 0; dt < 16; ++dt) {
#pragma unroll
                for (int r = 0; r < 4; ++r) {
                    long long row = qr0 + wq * 32 + s * 16 + quad * 4 + r;
                    Op[row * HID + h * HDIM + dt * 16 + tl] = (bf16_t)(oacc[s][dt][r] * inv[r]);
                }
            }
            if (quad == 0) {
                long long mi2 = ((long long)h * S_LEN + irow + s * 16) * 2;
                mlj[mi2] = m_i[s];
                mlj[mi2 + 1] = l_i[s];
            }
        }
    }
}

// ---------------- combine 4 k-quarter partials -> attnb ----------------
__global__ __launch_bounds__(256) void combine_kernel(const bf16_t* __restrict__ op0,
                                                      const bf16_t* __restrict__ opb123,
                                                      const float* __restrict__ mlb,
                                                      bf16_t* __restrict__ attnb) {
    int h = blockIdx.x;
    int row = blockIdx.y;
    int d = threadIdx.x;
    float m[4], l[4];
    float M = -3e38f;
#pragma unroll
    for (int j = 0; j < 4; ++j) {
        long long mi = (((long long)j * NHEADS + h) * S_LEN + row) * 2;
        m[j] = mlb[mi];
        l[j] = mlb[mi + 1];
        M = fmaxf(M, m[j]);
    }
    float wj[4], wsum = 0.f;
#pragma unroll
    for (int j = 0; j < 4; ++j) {
        wj[j] = (l[j] > 0.f) ? l[j] * __expf(m[j] - M) : 0.f;
        wsum += wj[j];
    }
    float inv = (wsum > 0.f) ? 1.0f / wsum : 0.f;
    long long idx = (long long)row * HID + h * HDIM + d;
    float acc = wj[0] * (float)op0[idx];
#pragma unroll
    for (int j = 1; j < 4; ++j)
        acc += wj[j] * (float)opb123[(long long)(j - 1) * (S_LEN * HID) + idx];
    attnb[idx] = (bf16_t)(acc * inv);
}

// ---------------- MFMA GEMM: C[M,N] = A[M,K] * Bt[N,K]^T (round-3 proven) ----------------
// 128x128 tile, BK=64, 256 threads (2x2 waves of 64x64), global_load_lds staging,
// XOR-swizzled LDS chunk layout (row-dense 128B global segments).
// MODE: 0 = bf16 store; 1 = fp32 store of aux+acc; 2 = bf16 store of gelu(aux)*acc;
// 3 = bf16 store of acc/16 (pre-scaled Q for attention).
template <int MODE>
__global__ __launch_bounds__(256) void gemm_kernel(const bf16_t* __restrict__ A, int lda,
                                                   const bf16_t* __restrict__ Bt, int ldb,
                                                   void* __restrict__ Cv, int ldc,
                                                   const void* __restrict__ aux, int K) {
    __shared__ bf16_t smem[2 * 128 * 64];
    bf16_t* sA = smem;
    bf16_t* sB = smem + 128 * 64;

    const int tid = threadIdx.x;
    const int n0 = blockIdx.x * 128;
    const int m0 = blockIdx.y * 128;

    const int lane = tid & 63;
    const int wid = tid >> 6;
    const int wm = (wid >> 1) * 64;
    const int wn = (wid & 1) * 64;
    const int tl = lane & 15;
    const int quad = lane >> 4;

    floatx4 acc[4][4] = {};

    for (int k0 = 0; k0 < K; k0 += 64) {
#pragma unroll
        for (int it = 0; it < 4; ++it) {
            int s = it * 256 + tid;      // 16B slot index 0..1023
            int m = s >> 3;              // tile row 0..127
            int sg = s & 7;              // stored chunk within row
            int g = sg ^ (m & 7);        // source chunk (XOR swizzle, self-inverse)
            const bf16_t* ga = A + (long long)(m0 + m) * lda + k0 + g * 8;
            __builtin_amdgcn_global_load_lds((const __attribute__((address_space(1))) void*)ga,
                                             (__attribute__((address_space(3))) void*)(sA + s * 8),
                                             16, 0, 0);
            const bf16_t* gb = Bt + (long long)(n0 + m) * ldb + k0 + g * 8;
            __builtin_amdgcn_global_load_lds((const __attribute__((address_space(1))) void*)gb,
                                             (__attribute__((address_space(3))) void*)(sB + s * 8),
                                             16, 0, 0);
        }
        __builtin_amdgcn_s_waitcnt(0x0f70);  // vmcnt(0)
        __syncthreads();

#pragma unroll
        for (int kk = 0; kk < 2; ++kk) {
            bf16x8 af[4], bfr[4];
#pragma unroll
            for (int mi = 0; mi < 4; ++mi) {
                int m = wm + mi * 16 + tl;
                int sg = (kk * 4 + quad) ^ (m & 7);
                af[mi] = *(const bf16x8*)(sA + m * 64 + sg * 8);
            }
#pragma unroll
            for (int ni = 0; ni < 4; ++ni) {
                int n = wn + ni * 16 + tl;
                int sg = (kk * 4 + quad) ^ (n & 7);
                bfr[ni] = *(const bf16x8*)(sB + n * 64 + sg * 8);
            }
#pragma unroll
            for (int mi = 0; mi < 4; ++mi)
#pragma unroll
                for (int ni = 0; ni < 4; ++ni)
                    acc[mi][ni] = __builtin_amdgcn_mfma_f32_16x16x32_bf16(af[mi], bfr[ni], acc[mi][ni], 0, 0, 0);
        }
        __syncthreads();
    }

    // epilogue: C/D layout col=lane&15, row=quad*4+r
#pragma unroll
    for (int mi = 0; mi < 4; ++mi) {
#pragma unroll
        for (int ni = 0; ni < 4; ++ni) {
#pragma unroll
            for (int r = 0; r < 4; ++r) {
                int gr = m0 + wm + mi * 16 + quad * 4 + r;
                int gc = n0 + wn + ni * 16 + tl;
                long long idx = (long long)gr * ldc + gc;
                float v = acc[mi][ni][r];
                if (MODE == 0) {
                    ((bf16_t*)Cv)[idx] = (bf16_t)v;
                } else if (MODE == 1) {
                    ((float*)Cv)[idx] = ((const float*)aux)[idx] + v;
                } else if (MODE == 2) {
                    float g = (float)((const bf16_t*)aux)[idx];
                    float t = 0.7978845608028654f * (g + 0.044715f * g * g * g);
                    float ge = 0.5f * g * (1.0f + tanhf(t));
                    ((bf16_t*)Cv)[idx] = (bf16_t)(ge * v);
                } else {
                    ((bf16_t*)Cv)[idx] = (bf16_t)(v * 0.0625f);
                }
            }
        }
    }
}

// ---------------- launch ----------------
extern "C" void kernel_launch(void* const* d_in, const int* in_sizes, int n_in,
                              void* d_out, int out_size, void* d_ws, size_t ws_size,
                              hipStream_t stream) {
    const float* hidden = (const float*)d_in[0];
    const float* q_w    = (const float*)d_in[1];
    const float* k_w    = (const float*)d_in[2];
    const float* v_w    = (const float*)d_in[3];
    const float* o_w    = (const float*)d_in[4];
    const float* gate_w = (const float*)d_in[5];
    const float* up_w   = (const float*)d_in[6];
    const float* down_w = (const float*)d_in[7];
    const float* ln1_w  = (const float*)d_in[8];
    const float* ln2_w  = (const float*)d_in[9];
    const int* amask    = (const int*)d_in[10];
    const int* pos_ids  = (const int*)d_in[11];
    float* out = (float*)d_out;

    // ---- workspace layout, time-shared (peak 193 MiB) ----
    const size_t MB = 1ull << 20;
    char* ws = (char*)d_ws;
    bf16_t* wqT    = (bf16_t*)(ws + 0 * MB);
    bf16_t* wkT    = (bf16_t*)(ws + 8 * MB);
    bf16_t* wvT    = (bf16_t*)(ws + 12 * MB);
    bf16_t* woT    = (bf16_t*)(ws + 16 * MB);
    bf16_t* wgT    = (bf16_t*)(ws + 24 * MB);
    bf16_t* wuT    = (bf16_t*)(ws + 56 * MB);
    bf16_t* xb     = (bf16_t*)(ws + 88 * MB);
    bf16_t* qb     = (bf16_t*)(ws + 104 * MB);
    bf16_t* kb     = (bf16_t*)(ws + 120 * MB);
    bf16_t* vb     = (bf16_t*)(ws + 128 * MB);
    bf16_t* vT     = (bf16_t*)(ws + 136 * MB);
    bf16_t* op0    = (bf16_t*)(ws + 88 * MB);   // over dead xb
    bf16_t* opb123 = (bf16_t*)(ws + 144 * MB);  // 3 x 16 MiB
    float*  mlb    = (float*) (ws + 192 * MB);  // 1 MiB
    bf16_t* attnb  = (bf16_t*)(ws + 104 * MB);  // over dead qb
    bf16_t* xb2    = (bf16_t*)(ws + 120 * MB);  // over dead kb+vb
    bf16_t* wdT    = (bf16_t*)(ws + 144 * MB);  // over opb123 (dead post-combine)
    bf16_t* gb     = (bf16_t*)(ws + 88 * MB);   // 32 MiB, over dead op0+attnb
    (void)ws_size; (void)in_sizes; (void)n_in; (void)out_size;

    dim3 blk(256);

    // weight transposes (attention + gate/up); down_w deferred
    transpose_bf16_kernel<float><<<dim3(64, 64), blk, 0, stream>>>(q_w, wqT, 2048, 2048);
    transpose_bf16_kernel<float><<<dim3(32, 64), blk, 0, stream>>>(k_w, wkT, 2048, 1024);
    transpose_bf16_kernel<float><<<dim3(32, 64), blk, 0, stream>>>(v_w, wvT, 2048, 1024);
    transpose_bf16_kernel<float><<<dim3(64, 64), blk, 0, stream>>>(o_w, woT, 2048, 2048);
    transpose_bf16_kernel<float><<<dim3(256, 64), blk, 0, stream>>>(gate_w, wgT, 2048, 8192);
    transpose_bf16_kernel<float><<<dim3(256, 64), blk, 0, stream>>>(up_w, wuT, 2048, 8192);

    // RMSNorm 1
    rmsnorm_kernel<<<dim3(S_LEN), blk, 0, stream>>>(hidden, ln1_w, xb);

    // QKV projections (Q pre-scaled by 1/16 via MODE 3)
    gemm_kernel<3><<<dim3(16, 32), blk, 0, stream>>>(xb, HID, wqT, HID, qb, 2048, nullptr, HID);
    gemm_kernel<0><<<dim3(8, 32), blk, 0, stream>>>(xb, HID, wkT, HID, kb, 1024, nullptr, HID);
    gemm_kernel<0><<<dim3(8, 32), blk, 0, stream>>>(xb, HID, wvT, HID, vb, 1024, nullptr, HID);

    // RoPE
    rope_kernel<<<dim3(S_LEN), blk, 0, stream>>>(qb, kb, pos_ids);

    // v^T for flash PV
    transpose_bf16_kernel<bf16_t><<<dim3(32, 128), blk, 0, stream>>>(vb, vT, S_LEN, 1024);

    // flash attention (GQA-shared 8-wave blocks) -> partials, then combine
    flash_attn_kernel<<<dim3(16, NKVH, 4), dim3(512), 0, stream>>>(qb, kb, vT, op0, opb123, mlb, amask);
    combine_kernel<<<dim3(NHEADS, S_LEN), blk, 0, stream>>>(op0, opb123, mlb, attnb);

    // O projection + residual into d_out (fp32)
    gemm_kernel<1><<<dim3(16, 32), blk, 0, stream>>>(attnb, 2048, woT, 2048, out, 2048, hidden, 2048);

    // RMSNorm 2
    rmsnorm_kernel<<<dim3(S_LEN), blk, 0, stream>>>(out, ln2_w, xb2);

    // down_w transpose into dead partial space
    transpose_bf16_kernel<float><<<dim3(64, 256), blk, 0, stream>>>(down_w, wdT, 8192, 2048);

    // MLP in two FFN-half chunks: gate -> gb, up (gelu*up in-place), down (+= into out)
    for (int c = 0; c < 2; ++c) {
        bf16_t* wgc = wgT + (size_t)c * 4096 * HID;
        bf16_t* wuc = wuT + (size_t)c * 4096 * HID;
        bf16_t* wdc = wdT + (size_t)c * 4096;
        gemm_kernel<0><<<dim3(32, 32), blk, 0, stream>>>(xb2, HID, wgc, HID, gb, 4096, nullptr, HID);
        gemm_kernel<2><<<dim3(32, 32), blk, 0, stream>>>(xb2, HID, wuc, HID, gb, 4096, gb, HID);
        gemm_kernel<1><<<dim3(16, 32), blk, 0, stream>>>(gb, 4096, wdc, FFN, out, 2048, out, 4096);
    }
}